// Round 1
// baseline (1263.390 us; speedup 1.0000x reference)
//
#include <hip/hip_runtime.h>

typedef short s8_t __attribute__((ext_vector_type(8)));
typedef float f4_t __attribute__((ext_vector_type(4)));

// ======================= compile-time Clebsch-Gordan =======================
namespace cgc {

struct Cx { double re, im; };

constexpr double FACT[13] = {1.,1.,2.,6.,24.,120.,720.,5040.,40320.,362880.,
                             3628800.,39916800.,479001600.};

constexpr double cfabs(double x){ return x < 0 ? -x : x; }

constexpr double csqrt(double x){
  if (x <= 0) return 0;
  double g = x > 1 ? x : 1.0;
  for (int i = 0; i < 80; ++i){
    double ng = 0.5*(g + x/g);
    if (ng == g) break;
    g = ng;
  }
  return g;
}

constexpr int imax3(int a,int b,int c){ int m=a; if(b>m)m=b; if(c>m)m=c; return m; }
constexpr int imin3(int a,int b,int c){ int m=a; if(b<m)m=b; if(c<m)m=c; return m; }

constexpr double clebsch(int j1,int m1,int j2,int m2,int j3,int m3){
  if (m1 + m2 != m3) return 0;
  const int jmin = j1 > j2 ? j1 - j2 : j2 - j1;
  if (j3 < jmin || j3 > j1 + j2) return 0;
  if (m1 < -j1 || m1 > j1 || m2 < -j2 || m2 > j2 || m3 < -j3 || m3 > j3) return 0;
  double pref = csqrt((2*j3+1)*FACT[j3+j1-j2]*FACT[j3-j1+j2]*FACT[j1+j2-j3]/FACT[j1+j2+j3+1]);
  pref *= csqrt(FACT[j3+m3]*FACT[j3-m3]*FACT[j1-m1]*FACT[j1+m1]*FACT[j2-m2]*FACT[j2+m2]);
  const int kmin = imax3(0, j2-j3-m1, j1-j3+m2);
  const int kmax = imin3(j1+j2-j3, j1-m1, j2+m2);
  double s = 0;
  for (int k = kmin; k <= kmax; ++k){
    double d = FACT[k]*FACT[j1+j2-j3-k]*FACT[j1-m1-k]*FACT[j2+m2-k]
             * FACT[j3-j2+m1+k]*FACT[j3-j1-m2+k];
    s += ((k & 1) ? -1.0 : 1.0) / d;
  }
  return pref * s;
}

constexpr Cx cmul(Cx a, Cx b){ return Cx{a.re*b.re - a.im*b.im, a.re*b.im + a.im*b.re}; }

// U[l+mr][l+mc] of the complex->real SH transform (row: real m, col: complex m)
constexpr Cx Uc2r(int mr, int mc){
  const double s2i = 0.70710678118654752440;
  if (mr == 0) return (mc == 0) ? Cx{1.,0.} : Cx{0.,0.};
  if (mr > 0){
    if (mc ==  mr) return Cx{ (mr & 1) ? -s2i : s2i, 0. };
    if (mc == -mr) return Cx{ s2i, 0. };
    return Cx{0.,0.};
  }
  const int m = -mr;
  if (mc ==  m) return Cx{0., (m & 1) ?  s2i : -s2i };
  if (mc == -m) return Cx{0., s2i };
  return Cx{0.,0.};
}

template<int L1,int L2,int L3>
struct CArr { float v[(2*L1+1)*(2*L2+1)*(2*L3+1)]; };

template<int L1,int L2,int L3>
constexpr CArr<L1,L2,L3> buildCG(){
  constexpr int D1 = 2*L1+1, D2 = 2*L2+1, D3 = 2*L3+1;
  // complex-basis CG cached once per coupling (m3 = m1+m2 enforced)
  double cgd[D1*D2] = {};
  for (int i = 0; i < D1; ++i)
    for (int j = 0; j < D2; ++j){
      const int m1c = i - L1, m2c = j - L2, m3c = m1c + m2c;
      cgd[i*D2+j] = (m3c < -L3 || m3c > L3) ? 0.0 : clebsch(L1,m1c,L2,m2c,L3,m3c);
    }
  double tre[D1*D2*D3] = {};
  double tim[D1*D2*D3] = {};
  for (int a = 0; a < D1; ++a)
  for (int b = 0; b < D2; ++b)
  for (int c = 0; c < D3; ++c){
    const int m1r = a - L1, m2r = b - L2, m3r = c - L3;
    double sre = 0, sim = 0;
    const int n1 = (m1r == 0) ? 1 : 2;
    const int n2 = (m2r == 0) ? 1 : 2;
    for (int ii = 0; ii < n1; ++ii)
    for (int jj = 0; jj < n2; ++jj){
      const int m1c = ii ? -m1r : m1r;
      const int m2c = jj ? -m2r : m2r;
      const int m3c = m1c + m2c;
      if (m3c < -L3 || m3c > L3) continue;
      const Cx u3 = Uc2r(m3r, m3c);
      if (u3.re == 0 && u3.im == 0) continue;
      const double cgv = cgd[(L1+m1c)*D2 + (L2+m2c)];
      if (cgv == 0) continue;
      const Cx u1 = Uc2r(m1r, m1c);
      const Cx u2 = Uc2r(m2r, m2c);
      const Cx p  = cmul(u1, u2);
      const Cx t  = cmul(p, Cx{u3.re, -u3.im});   // conj(U3)
      sre += t.re * cgv;
      sim += t.im * cgv;
    }
    tre[(a*D2+b)*D3+c] = sre;
    tim[(a*D2+b)*D3+c] = sim;
  }
  // tensor is purely real or purely imaginary; pick like the reference
  double mre = 0, mim = 0;
  for (int k = 0; k < D1*D2*D3; ++k){
    if (cfabs(tre[k]) > mre) mre = cfabs(tre[k]);
    if (cfabs(tim[k]) > mim) mim = cfabs(tim[k]);
  }
  CArr<L1,L2,L3> o{};
  for (int k = 0; k < D1*D2*D3; ++k)
    o.v[k] = (float)((mre >= mim) ? tre[k] : tim[k]);
  return o;
}

template<int L1,int L2,int L3>
constexpr CArr<L1,L2,L3> CG_V = buildCG<L1,L2,L3>();

constexpr int lminf(int a,int b){ return a > b ? a - b : b - a; }
constexpr int lmaxf(int a,int b){ return (a + b < 4) ? (a + b) : 4; }
constexpr int cplIndex(int l1,int l2,int lo){
  int idx = 0;
  for (int a = 0; a <= 3; ++a)
    for (int b = 0; b <= 3; ++b){
      const int c0 = lminf(a,b), c1 = lmaxf(a,b);
      for (int c = c0; c <= c1; ++c){
        if (a == l1 && b == l2 && c == lo) return idx;
        ++idx;
      }
    }
  return -1;
}
constexpr int poff(int l1,int l2,int lo){
  int s = 0;
  for (int c = lminf(l1,l2); c < lo; ++c) s += 2*c + 1;
  return s;
}
constexpr int psize(int l1,int l2){ return poff(l1, l2, lmaxf(l1,l2) + 1); }

} // namespace cgc

// ======================= device helpers =======================
__device__ __forceinline__ unsigned short f2bf(float x){
  unsigned u = __float_as_uint(x);
  u += 0x7fffu + ((u >> 16) & 1u);       // RNE
  return (unsigned short)(u >> 16);
}
__device__ __forceinline__ float bf2f(unsigned short h){
  return __uint_as_float(((unsigned)h) << 16);
}

// W pre-packed into bf16 MFMA B-fragment order: [i][ntile][kstep][lane][8]
__device__ __attribute__((aligned(16))) unsigned short WF[81920];

// ---- CG accumulation machinery (all indices fold to constants) ----
template<int L1,int L2,int LO,int LMAX>
struct LoutAccum {
  static __device__ __forceinline__ void run(float t, int pq, float* part){
    constexpr int D3 = 2*LO + 1;
    #pragma unroll
    for (int m = 0; m < D3; ++m){
      const float cg = cgc::CG_V<L1,L2,LO>.v[pq*D3 + m];
      if (cg > 1e-7f || cg < -1e-7f)
        part[cgc::poff(L1,L2,LO) + m] += cg * t;
    }
    if constexpr (LO < LMAX) LoutAccum<L1,L2,LO+1,LMAX>::run(t, pq, part);
  }
};

template<int L1,int L2,int LO,int LMAX>
struct ScaleAccum {
  static __device__ __forceinline__ void run(const float* part, float* acc,
                                             const unsigned short* fR){
    constexpr int I = cgc::cplIndex(L1,L2,LO);
    const float fv = bf2f(fR[I*32]);
    #pragma unroll
    for (int m = 0; m < 2*LO + 1; ++m)
      acc[LO*LO + m] = fmaf(fv, part[cgc::poff(L1,L2,LO) + m], acc[LO*LO + m]);
    if constexpr (LO < LMAX) ScaleAccum<L1,L2,LO+1,LMAX>::run(part, acc, fR);
  }
};

template<int L1,int L2>
__device__ __forceinline__ void doGroup(const float* xr, const float* yr,
                                        float* acc, const unsigned short* fR){
  constexpr int LMIN = cgc::lminf(L1,L2), LMAX = cgc::lmaxf(L1,L2);
  constexpr int D1 = 2*L1 + 1, D2 = 2*L2 + 1;
  float part[cgc::psize(L1,L2)];
  #pragma unroll
  for (int s = 0; s < cgc::psize(L1,L2); ++s) part[s] = 0.f;
  #pragma unroll
  for (int p = 0; p < D1; ++p){
    const float xv = xr[L1*L1 + p];
    #pragma unroll
    for (int q = 0; q < D2; ++q){
      const float t = xv * yr[L2*L2 + q];
      LoutAccum<L1,L2,LMIN,LMAX>::run(t, p*D2 + q, part);
    }
  }
  ScaleAccum<L1,L2,LMIN,LMAX>::run(part, acc, fR);
}

// ======================= kernels =======================
__global__ __launch_bounds__(256) void prep_wf(const float* __restrict__ W){
  const int idx = blockIdx.x*256 + threadIdx.x;         // 81920 total
  const int j = idx & 7;
  const int l = (idx >> 3) & 63;
  const int s = (idx >> 9) & 1;
  const int t = (idx >> 10) & 1;
  const int i = idx >> 11;
  const int k   = s*32 + ((l >> 4) << 3) + j;           // contiguous-8 k per lane
  const int col = (t << 4) + (l & 15);
  WF[idx] = f2bf(W[(i << 11) + (k << 5) + col]);
}

__global__ __launch_bounds__(512) void pairmix(const float* __restrict__ x,
                                               const float* __restrict__ y,
                                               const float* __restrict__ r,
                                               float* __restrict__ out){
  __shared__ unsigned short Fmat[16][1280];             // f_i[e][i*32+n] bf16, 40 KB
  const int e0   = blockIdx.x << 4;                     // 16 edges per block
  const int tid  = threadIdx.x;
  const int lane = tid & 63;
  const int wv   = tid >> 6;                            // 0..7

  // ---- Phase 1: Fmat = r @ W via bf16 MFMA (M=16 edges, N=1280, K=64) ----
  {
    const int mrow = lane & 15;                         // edge row
    const int kch  = (lane >> 4) << 3;                  // k chunk base
    const float* rp = r + (size_t)(e0 + mrow)*64 + kch;
    s8_t A[2];
    #pragma unroll
    for (int s = 0; s < 2; ++s){
      const float4 v0 = *(const float4*)(rp + s*32);
      const float4 v1 = *(const float4*)(rp + s*32 + 4);
      union { s8_t v; unsigned u[4]; } pk;
      pk.u[0] = (unsigned)f2bf(v0.x) | ((unsigned)f2bf(v0.y) << 16);
      pk.u[1] = (unsigned)f2bf(v0.z) | ((unsigned)f2bf(v0.w) << 16);
      pk.u[2] = (unsigned)f2bf(v1.x) | ((unsigned)f2bf(v1.y) << 16);
      pk.u[3] = (unsigned)f2bf(v1.z) | ((unsigned)f2bf(v1.w) << 16);
      A[s] = pk.v;
    }
    #pragma unroll
    for (int tt = 0; tt < 10; ++tt){                    // 8 waves x 10 = 80 tiles
      const int T  = wv*10 + tt;
      const int ci = T >> 1;                            // coupling 0..39
      const int th = T & 1;                             // n-half 0..1
      const s8_t B0 = *(const s8_t*)(WF + ((((ci*2 + th)*2 + 0)*64 + lane) << 3));
      const s8_t B1 = *(const s8_t*)(WF + ((((ci*2 + th)*2 + 1)*64 + lane) << 3));
      f4_t c = {0.f, 0.f, 0.f, 0.f};
      c = __builtin_amdgcn_mfma_f32_16x16x32_bf16(A[0], B0, c, 0, 0, 0);
      c = __builtin_amdgcn_mfma_f32_16x16x32_bf16(A[1], B1, c, 0, 0, 0);
      const int col = ci*32 + th*16 + (lane & 15);
      const int rb  = (lane >> 4) << 2;
      #pragma unroll
      for (int jj = 0; jj < 4; ++jj)
        Fmat[rb + jj][col] = f2bf(c[jj]);               // C/D: col=lane&15, row=(lane>>4)*4+reg
    }
  }
  __syncthreads();

  // ---- Phase 2: CG contraction, one thread per (edge, channel) ----
  const int n  = tid & 31;
  const int el = tid >> 5;                              // 0..15
  const float* xp = x + (size_t)(e0 + el)*512 + n;
  const float* yp = y + (size_t)(e0 + el)*512 + n;
  float xr_[16], yr_[16];
  #pragma unroll
  for (int s = 0; s < 16; ++s){ xr_[s] = xp[s << 5]; yr_[s] = yp[s << 5]; }
  float acc[25];
  #pragma unroll
  for (int s = 0; s < 25; ++s) acc[s] = 0.f;
  const unsigned short* fR = &Fmat[el][n];

  doGroup<0,0>(xr_, yr_, acc, fR);
  doGroup<0,1>(xr_, yr_, acc, fR);
  doGroup<0,2>(xr_, yr_, acc, fR);
  doGroup<0,3>(xr_, yr_, acc, fR);
  doGroup<1,0>(xr_, yr_, acc, fR);
  doGroup<1,1>(xr_, yr_, acc, fR);
  doGroup<1,2>(xr_, yr_, acc, fR);
  doGroup<1,3>(xr_, yr_, acc, fR);
  doGroup<2,0>(xr_, yr_, acc, fR);
  doGroup<2,1>(xr_, yr_, acc, fR);
  doGroup<2,2>(xr_, yr_, acc, fR);
  doGroup<2,3>(xr_, yr_, acc, fR);
  doGroup<3,0>(xr_, yr_, acc, fR);
  doGroup<3,1>(xr_, yr_, acc, fR);
  doGroup<3,2>(xr_, yr_, acc, fR);
  doGroup<3,3>(xr_, yr_, acc, fR);

  float* op = out + (size_t)(e0 + el)*800 + n;
  #pragma unroll
  for (int s = 0; s < 25; ++s) op[s << 5] = acc[s];
}

// ======================= launch =======================
extern "C" void kernel_launch(void* const* d_in, const int* in_sizes, int n_in,
                              void* d_out, int out_size, void* d_ws, size_t ws_size,
                              hipStream_t stream){
  const float* x = (const float*)d_in[0];
  const float* y = (const float*)d_in[1];
  const float* r = (const float*)d_in[2];
  const float* W = (const float*)d_in[3];
  float* out = (float*)d_out;

  const int E = in_sizes[0] / 512;                      // 100000

  prep_wf<<<320, 256, 0, stream>>>(W);                  // 81920 threads
  pairmix<<<E / 16, 512, 0, stream>>>(x, y, r, out);
}

// Round 2
// 193.151 us; speedup vs baseline: 6.5410x; 6.5410x over previous
//
#include <hip/hip_runtime.h>

typedef short s8_t __attribute__((ext_vector_type(8)));
typedef float f4_t __attribute__((ext_vector_type(4)));

// ======================= compile-time Clebsch-Gordan =======================
namespace cgc {

struct Cx { double re, im; };

constexpr double FACT[13] = {1.,1.,2.,6.,24.,120.,720.,5040.,40320.,362880.,
                             3628800.,39916800.,479001600.};

constexpr double cfabs(double x){ return x < 0 ? -x : x; }

constexpr double csqrt(double x){
  if (x <= 0) return 0;
  double g = x > 1 ? x : 1.0;
  for (int i = 0; i < 80; ++i){
    double ng = 0.5*(g + x/g);
    if (ng == g) break;
    g = ng;
  }
  return g;
}

constexpr int imax3(int a,int b,int c){ int m=a; if(b>m)m=b; if(c>m)m=c; return m; }
constexpr int imin3(int a,int b,int c){ int m=a; if(b<m)m=b; if(c<m)m=c; return m; }

constexpr double clebsch(int j1,int m1,int j2,int m2,int j3,int m3){
  if (m1 + m2 != m3) return 0;
  const int jmin = j1 > j2 ? j1 - j2 : j2 - j1;
  if (j3 < jmin || j3 > j1 + j2) return 0;
  if (m1 < -j1 || m1 > j1 || m2 < -j2 || m2 > j2 || m3 < -j3 || m3 > j3) return 0;
  double pref = csqrt((2*j3+1)*FACT[j3+j1-j2]*FACT[j3-j1+j2]*FACT[j1+j2-j3]/FACT[j1+j2+j3+1]);
  pref *= csqrt(FACT[j3+m3]*FACT[j3-m3]*FACT[j1-m1]*FACT[j1+m1]*FACT[j2-m2]*FACT[j2+m2]);
  const int kmin = imax3(0, j2-j3-m1, j1-j3+m2);
  const int kmax = imin3(j1+j2-j3, j1-m1, j2+m2);
  double s = 0;
  for (int k = kmin; k <= kmax; ++k){
    double d = FACT[k]*FACT[j1+j2-j3-k]*FACT[j1-m1-k]*FACT[j2+m2-k]
             * FACT[j3-j2+m1+k]*FACT[j3-j1-m2+k];
    s += ((k & 1) ? -1.0 : 1.0) / d;
  }
  return pref * s;
}

constexpr Cx cmul(Cx a, Cx b){ return Cx{a.re*b.re - a.im*b.im, a.re*b.im + a.im*b.re}; }

// U[l+mr][l+mc] of the complex->real SH transform (row: real m, col: complex m)
constexpr Cx Uc2r(int mr, int mc){
  const double s2i = 0.70710678118654752440;
  if (mr == 0) return (mc == 0) ? Cx{1.,0.} : Cx{0.,0.};
  if (mr > 0){
    if (mc ==  mr) return Cx{ (mr & 1) ? -s2i : s2i, 0. };
    if (mc == -mr) return Cx{ s2i, 0. };
    return Cx{0.,0.};
  }
  const int m = -mr;
  if (mc ==  m) return Cx{0., (m & 1) ?  s2i : -s2i };
  if (mc == -m) return Cx{0., s2i };
  return Cx{0.,0.};
}

template<int L1,int L2,int L3>
struct CArr { float v[(2*L1+1)*(2*L2+1)*(2*L3+1)]; };

template<int L1,int L2,int L3>
constexpr CArr<L1,L2,L3> buildCG(){
  constexpr int D1 = 2*L1+1, D2 = 2*L2+1, D3 = 2*L3+1;
  // complex-basis CG cached once per coupling (m3 = m1+m2 enforced)
  double cgd[D1*D2] = {};
  for (int i = 0; i < D1; ++i)
    for (int j = 0; j < D2; ++j){
      const int m1c = i - L1, m2c = j - L2, m3c = m1c + m2c;
      cgd[i*D2+j] = (m3c < -L3 || m3c > L3) ? 0.0 : clebsch(L1,m1c,L2,m2c,L3,m3c);
    }
  double tre[D1*D2*D3] = {};
  double tim[D1*D2*D3] = {};
  for (int a = 0; a < D1; ++a)
  for (int b = 0; b < D2; ++b)
  for (int c = 0; c < D3; ++c){
    const int m1r = a - L1, m2r = b - L2, m3r = c - L3;
    double sre = 0, sim = 0;
    const int n1 = (m1r == 0) ? 1 : 2;
    const int n2 = (m2r == 0) ? 1 : 2;
    for (int ii = 0; ii < n1; ++ii)
    for (int jj = 0; jj < n2; ++jj){
      const int m1c = ii ? -m1r : m1r;
      const int m2c = jj ? -m2r : m2r;
      const int m3c = m1c + m2c;
      if (m3c < -L3 || m3c > L3) continue;
      const Cx u3 = Uc2r(m3r, m3c);
      if (u3.re == 0 && u3.im == 0) continue;
      const double cgv = cgd[(L1+m1c)*D2 + (L2+m2c)];
      if (cgv == 0) continue;
      const Cx u1 = Uc2r(m1r, m1c);
      const Cx u2 = Uc2r(m2r, m2c);
      const Cx p  = cmul(u1, u2);
      const Cx t  = cmul(p, Cx{u3.re, -u3.im});   // conj(U3)
      sre += t.re * cgv;
      sim += t.im * cgv;
    }
    tre[(a*D2+b)*D3+c] = sre;
    tim[(a*D2+b)*D3+c] = sim;
  }
  // tensor is purely real or purely imaginary; pick like the reference
  double mre = 0, mim = 0;
  for (int k = 0; k < D1*D2*D3; ++k){
    if (cfabs(tre[k]) > mre) mre = cfabs(tre[k]);
    if (cfabs(tim[k]) > mim) mim = cfabs(tim[k]);
  }
  CArr<L1,L2,L3> o{};
  for (int k = 0; k < D1*D2*D3; ++k)
    o.v[k] = (float)((mre >= mim) ? tre[k] : tim[k]);
  return o;
}

template<int L1,int L2,int L3>
constexpr CArr<L1,L2,L3> CG_V = buildCG<L1,L2,L3>();

constexpr int lminf(int a,int b){ return a > b ? a - b : b - a; }
constexpr int lmaxf(int a,int b){ return (a + b < 4) ? (a + b) : 4; }
constexpr int cplIndex(int l1,int l2,int lo){
  int idx = 0;
  for (int a = 0; a <= 3; ++a)
    for (int b = 0; b <= 3; ++b){
      const int c0 = lminf(a,b), c1 = lmaxf(a,b);
      for (int c = c0; c <= c1; ++c){
        if (a == l1 && b == l2 && c == lo) return idx;
        ++idx;
      }
    }
  return -1;
}
constexpr int poff(int l1,int l2,int lo){
  int s = 0;
  for (int c = lminf(l1,l2); c < lo; ++c) s += 2*c + 1;
  return s;
}
constexpr int psize(int l1,int l2){ return poff(l1, l2, lmaxf(l1,l2) + 1); }

} // namespace cgc

// ======================= device helpers =======================
__device__ __forceinline__ unsigned short f2bf(float x){
  unsigned u = __float_as_uint(x);
  u += 0x7fffu + ((u >> 16) & 1u);       // RNE
  return (unsigned short)(u >> 16);
}
__device__ __forceinline__ float bf2f(unsigned short h){
  return __uint_as_float(((unsigned)h) << 16);
}

// W pre-packed into bf16 MFMA B-fragment order: [i][ntile][kstep][lane][8]
__device__ __attribute__((aligned(16))) unsigned short WF[81920];

// ---- CG accumulation: ALL indices are template params -> coefficients are
// compile-time literals, zeros deleted by if constexpr (round-1 bug: pq was a
// runtime arg -> 5110 global loads + runtime branches per thread).
template<int L1,int L2,int PQ,int LO,int LMAX,int M>
struct EmitM {
  static __device__ __forceinline__ void run(float t, float* __restrict__ part){
    constexpr float cg = cgc::CG_V<L1,L2,LO>.v[PQ*(2*LO+1) + M];
    if constexpr (cg > 1e-7f || cg < -1e-7f)
      part[cgc::poff(L1,L2,LO) + M] = fmaf(cg, t, part[cgc::poff(L1,L2,LO) + M]);
    if constexpr (M + 1 < 2*LO + 1)
      EmitM<L1,L2,PQ,LO,LMAX,M+1>::run(t, part);
    else if constexpr (LO < LMAX)
      EmitM<L1,L2,PQ,LO+1,LMAX,0>::run(t, part);
  }
};

template<int L1,int L2,int P,int Q>
struct PQLoop {
  static __device__ __forceinline__ void run(const float* __restrict__ xr,
                                             const float* __restrict__ yr,
                                             float* __restrict__ part){
    const float t = xr[L1*L1 + P] * yr[L2*L2 + Q];
    EmitM<L1, L2, P*(2*L2+1)+Q, cgc::lminf(L1,L2), cgc::lmaxf(L1,L2), 0>::run(t, part);
    if constexpr (Q + 1 < 2*L2 + 1)
      PQLoop<L1,L2,P,Q+1>::run(xr, yr, part);
    else if constexpr (P + 1 < 2*L1 + 1)
      PQLoop<L1,L2,P+1,0>::run(xr, yr, part);
  }
};

template<int L1,int L2,int LO,int LMAX>
struct ScaleAccum {
  static __device__ __forceinline__ void run(const float* __restrict__ part,
                                             float* __restrict__ acc,
                                             const unsigned short* __restrict__ fR){
    constexpr int I = cgc::cplIndex(L1,L2,LO);
    const float fv = bf2f(fR[I*32]);
    #pragma unroll
    for (int m = 0; m < 2*LO + 1; ++m)
      acc[LO*LO + m] = fmaf(fv, part[cgc::poff(L1,L2,LO) + m], acc[LO*LO + m]);
    if constexpr (LO < LMAX) ScaleAccum<L1,L2,LO+1,LMAX>::run(part, acc, fR);
  }
};

template<int L1,int L2>
__device__ __forceinline__ void doGroup(const float* __restrict__ xr,
                                        const float* __restrict__ yr,
                                        float* __restrict__ acc,
                                        const unsigned short* __restrict__ fR){
  float part[cgc::psize(L1,L2)];
  #pragma unroll
  for (int s = 0; s < cgc::psize(L1,L2); ++s) part[s] = 0.f;
  PQLoop<L1,L2,0,0>::run(xr, yr, part);
  ScaleAccum<L1,L2,cgc::lminf(L1,L2),cgc::lmaxf(L1,L2)>::run(part, acc, fR);
}

// ======================= kernels =======================
__global__ __launch_bounds__(256) void prep_wf(const float* __restrict__ W){
  const int idx = blockIdx.x*256 + threadIdx.x;         // 81920 total
  const int j = idx & 7;
  const int l = (idx >> 3) & 63;
  const int s = (idx >> 9) & 1;
  const int t = (idx >> 10) & 1;
  const int i = idx >> 11;
  const int k   = s*32 + ((l >> 4) << 3) + j;           // contiguous-8 k per lane
  const int col = (t << 4) + (l & 15);
  WF[idx] = f2bf(W[(i << 11) + (k << 5) + col]);
}

#define FROW 1312   // 1280 + 32 pad: row stride 656 dwords == 16 mod 32 -> half-waves hit disjoint banks

__global__ __launch_bounds__(512) void pairmix(const float* __restrict__ x,
                                               const float* __restrict__ y,
                                               const float* __restrict__ r,
                                               float* __restrict__ out){
  __shared__ unsigned short Fmat[16][FROW];             // f_i[e][i*32+n] bf16, 41 KB
  const int e0   = blockIdx.x << 4;                     // 16 edges per block
  const int tid  = threadIdx.x;
  const int lane = tid & 63;
  const int wv   = tid >> 6;                            // 0..7

  // ---- Phase 1: Fmat = r @ W via bf16 MFMA (M=16 edges, N=1280, K=64) ----
  {
    const int mrow = lane & 15;                         // edge row
    const int kch  = (lane >> 4) << 3;                  // k chunk base
    const float* rp = r + (size_t)(e0 + mrow)*64 + kch;
    s8_t A[2];
    #pragma unroll
    for (int s = 0; s < 2; ++s){
      const float4 v0 = *(const float4*)(rp + s*32);
      const float4 v1 = *(const float4*)(rp + s*32 + 4);
      union { s8_t v; unsigned u[4]; } pk;
      pk.u[0] = (unsigned)f2bf(v0.x) | ((unsigned)f2bf(v0.y) << 16);
      pk.u[1] = (unsigned)f2bf(v0.z) | ((unsigned)f2bf(v0.w) << 16);
      pk.u[2] = (unsigned)f2bf(v1.x) | ((unsigned)f2bf(v1.y) << 16);
      pk.u[3] = (unsigned)f2bf(v1.z) | ((unsigned)f2bf(v1.w) << 16);
      A[s] = pk.v;
    }
    #pragma unroll
    for (int tt = 0; tt < 10; ++tt){                    // 8 waves x 10 = 80 tiles
      const int T  = wv*10 + tt;
      const int ci = T >> 1;                            // coupling 0..39
      const int th = T & 1;                             // n-half 0..1
      const s8_t B0 = *(const s8_t*)(WF + ((((ci*2 + th)*2 + 0)*64 + lane) << 3));
      const s8_t B1 = *(const s8_t*)(WF + ((((ci*2 + th)*2 + 1)*64 + lane) << 3));
      f4_t c = {0.f, 0.f, 0.f, 0.f};
      c = __builtin_amdgcn_mfma_f32_16x16x32_bf16(A[0], B0, c, 0, 0, 0);
      c = __builtin_amdgcn_mfma_f32_16x16x32_bf16(A[1], B1, c, 0, 0, 0);
      const int col = ci*32 + th*16 + (lane & 15);
      const int rb  = (lane >> 4) << 2;
      #pragma unroll
      for (int jj = 0; jj < 4; ++jj)
        Fmat[rb + jj][col] = f2bf(c[jj]);               // C/D: col=lane&15, row=(lane>>4)*4+reg
    }
  }
  __syncthreads();

  // ---- Phase 2: CG contraction, one thread per (edge, channel) ----
  const int n  = tid & 31;
  const int el = tid >> 5;                              // 0..15
  const float* xp = x + (size_t)(e0 + el)*512 + n;
  const float* yp = y + (size_t)(e0 + el)*512 + n;
  float xr_[16], yr_[16];
  #pragma unroll
  for (int s = 0; s < 16; ++s){ xr_[s] = xp[s << 5]; yr_[s] = yp[s << 5]; }
  float acc[25];
  #pragma unroll
  for (int s = 0; s < 25; ++s) acc[s] = 0.f;
  const unsigned short* fR = &Fmat[el][n];

  doGroup<0,0>(xr_, yr_, acc, fR);
  doGroup<0,1>(xr_, yr_, acc, fR);
  doGroup<0,2>(xr_, yr_, acc, fR);
  doGroup<0,3>(xr_, yr_, acc, fR);
  doGroup<1,0>(xr_, yr_, acc, fR);
  doGroup<1,1>(xr_, yr_, acc, fR);
  doGroup<1,2>(xr_, yr_, acc, fR);
  doGroup<1,3>(xr_, yr_, acc, fR);
  doGroup<2,0>(xr_, yr_, acc, fR);
  doGroup<2,1>(xr_, yr_, acc, fR);
  doGroup<2,2>(xr_, yr_, acc, fR);
  doGroup<2,3>(xr_, yr_, acc, fR);
  doGroup<3,0>(xr_, yr_, acc, fR);
  doGroup<3,1>(xr_, yr_, acc, fR);
  doGroup<3,2>(xr_, yr_, acc, fR);
  doGroup<3,3>(xr_, yr_, acc, fR);

  float* op = out + (size_t)(e0 + el)*800 + n;
  #pragma unroll
  for (int s = 0; s < 25; ++s) op[s << 5] = acc[s];
}

// ======================= launch =======================
extern "C" void kernel_launch(void* const* d_in, const int* in_sizes, int n_in,
                              void* d_out, int out_size, void* d_ws, size_t ws_size,
                              hipStream_t stream){
  const float* x = (const float*)d_in[0];
  const float* y = (const float*)d_in[1];
  const float* r = (const float*)d_in[2];
  const float* W = (const float*)d_in[3];
  float* out = (float*)d_out;

  const int E = in_sizes[0] / 512;                      // 100000

  prep_wf<<<320, 256, 0, stream>>>(W);                  // 81920 threads
  pairmix<<<E / 16, 512, 0, stream>>>(x, y, r, out);
}